// Round 3
// baseline (171.201 us; speedup 1.0000x reference)
//
#include <hip/hip_runtime.h>

// SSIM loss, fused single-pass implementation. (Round-2 resubmit: rounds 0-1
// never ran — GPU broker timeouts. Architecture unchanged; no evidence yet.)
// Geometry: input 16 x 3 x 512 x 512 f32; shave 10 -> Y-plane 16 x 492 x 492;
// five 11x11 zero-padded box filters; SSIM map; scalar sum / 16.

#define IMG    512
#define SHAVE  10
#define OUTW   492            // 512 - 2*SHAVE
#define TILE   32
#define HALO   5
#define REG    (TILE + 2*HALO)   // 42
#define NTILES 16             // ceil(492/32)
#define NBATCH 16

__global__ __launch_bounds__(256)
void ssim_tile_kernel(const float* __restrict__ sr,
                      const float* __restrict__ hr,
                      double* __restrict__ acc)
{
    __shared__ float ys[REG][REG];      // Y(sr), shaved coords, zero padded
    __shared__ float yh[REG][REG];      // Y(hr)
    __shared__ float hsS [REG][TILE];   // horizontal 11-sums
    __shared__ float hsH [REG][TILE];
    __shared__ float hsSS[REG][TILE];
    __shared__ float hsHH[REG][TILE];
    __shared__ float hsSH[REG][TILE];
    __shared__ float wpart[4];

    const int b   = blockIdx.z;
    const int oy0 = blockIdx.y * TILE;
    const int ox0 = blockIdx.x * TILE;
    const int tid = threadIdx.x;

    const float inv255 = 1.0f / 255.0f;
    const float w0 = 65.738f  / 256.0f;
    const float w1 = 129.057f / 256.0f;
    const float w2 = 25.064f  / 256.0f;

    const size_t cstride = (size_t)IMG * IMG;          // channel stride
    const size_t base    = (size_t)b * 3 * cstride;

    // ---- stage 1: global -> LDS, fused clip + RGB->Y, zero pad ----
    for (int i = tid; i < REG * REG; i += 256) {
        const int r  = i / REG;
        const int c  = i - r * REG;
        const int sy = oy0 - HALO + r;   // shaved coords
        const int sx = ox0 - HALO + c;
        const size_t idx = base + (size_t)(sy + SHAVE) * IMG + (sx + SHAVE);
        float vs = 0.0f, vh = 0.0f;
        if (sy >= 0 && sy < OUTW && sx >= 0 && sx < OUTW) {
            float s0 = fminf(fmaxf(sr[idx]               * inv255, 0.0f), 1.0f);
            float s1 = fminf(fmaxf(sr[idx +     cstride] * inv255, 0.0f), 1.0f);
            float s2 = fminf(fmaxf(sr[idx + 2 * cstride] * inv255, 0.0f), 1.0f);
            float h0 = fminf(fmaxf(hr[idx]               * inv255, 0.0f), 1.0f);
            float h1 = fminf(fmaxf(hr[idx +     cstride] * inv255, 0.0f), 1.0f);
            float h2 = fminf(fmaxf(hr[idx + 2 * cstride] * inv255, 0.0f), 1.0f);
            vs = w0 * s0 + w1 * s1 + w2 * s2;
            vh = w0 * h0 + w1 * h1 + w2 * h2;
        }
        ys[r][c] = vs;
        yh[r][c] = vh;
    }
    __syncthreads();

    // ---- stage 2: horizontal 11-tap sums of (s, h, s^2, h^2, s*h) ----
    for (int i = tid; i < REG * TILE; i += 256) {
        const int r = i >> 5;            // / TILE (32)
        const int c = i & (TILE - 1);
        float s = 0.f, h = 0.f, ss = 0.f, hh = 0.f, sh = 0.f;
#pragma unroll
        for (int dx = 0; dx < 11; ++dx) {
            const float a = ys[r][c + dx];
            const float g = yh[r][c + dx];
            s  += a;     h  += g;
            ss += a * a; hh += g * g; sh += a * g;
        }
        hsS [r][c] = s;  hsH [r][c] = h;
        hsSS[r][c] = ss; hsHH[r][c] = hh; hsSH[r][c] = sh;
    }
    __syncthreads();

    // ---- stage 3: vertical 11-tap sums + SSIM ----
    const float C1 = 6.5025f;     // (0.01*255)^2
    const float C2 = 58.5225f;    // (0.03*255)^2
    const float inv121 = 1.0f / 121.0f;
    float local = 0.0f;
    for (int p = tid; p < TILE * TILE; p += 256) {
        const int oyl = p >> 5;
        const int oxl = p & (TILE - 1);
        const int oy  = oy0 + oyl;
        const int ox  = ox0 + oxl;
        if (oy < OUTW && ox < OUTW) {
            float s = 0.f, h = 0.f, ss = 0.f, hh = 0.f, sh = 0.f;
#pragma unroll
            for (int dy = 0; dy < 11; ++dy) {
                s  += hsS [oyl + dy][oxl];
                h  += hsH [oyl + dy][oxl];
                ss += hsSS[oyl + dy][oxl];
                hh += hsHH[oyl + dy][oxl];
                sh += hsSH[oyl + dy][oxl];
            }
            const float mu1   = s * inv121;
            const float mu2   = h * inv121;
            const float mu1sq = mu1 * mu1;
            const float mu2sq = mu2 * mu2;
            const float mu12  = mu1 * mu2;
            const float sig1  = ss * inv121 - mu1sq;
            const float sig2  = hh * inv121 - mu2sq;
            const float sig12 = sh * inv121 - mu12;
            const float num = (2.0f * mu12 + C1) * (2.0f * sig12 + C2);
            const float den = (mu1sq + mu2sq + C1) * (sig1 + sig2 + C2);
            local += 1.0f - num / den;
        }
    }

    // ---- block reduction: wave shfl (64 lanes) -> LDS -> atomic double ----
#pragma unroll
    for (int off = 32; off > 0; off >>= 1)
        local += __shfl_down(local, off, 64);
    const int lane = tid & 63;
    const int wv   = tid >> 6;
    if (lane == 0) wpart[wv] = local;
    __syncthreads();
    if (tid == 0) {
        const float tot = wpart[0] + wpart[1] + wpart[2] + wpart[3];
        atomicAdd(acc, (double)tot);
    }
}

__global__ void ssim_finalize(const double* __restrict__ acc,
                              float* __restrict__ out)
{
    out[0] = (float)(acc[0] / (double)NBATCH);
}

extern "C" void kernel_launch(void* const* d_in, const int* in_sizes, int n_in,
                              void* d_out, int out_size, void* d_ws, size_t ws_size,
                              hipStream_t stream)
{
    const float* sr = (const float*)d_in[0];
    const float* hr = (const float*)d_in[1];
    double* acc = (double*)d_ws;
    float* out  = (float*)d_out;

    // ws is poisoned 0xAA before every launch -> zero the accumulator.
    hipMemsetAsync(d_ws, 0, sizeof(double), stream);

    dim3 grid(NTILES, NTILES, NBATCH);
    ssim_tile_kernel<<<grid, 256, 0, stream>>>(sr, hr, acc);
    ssim_finalize<<<1, 1, 0, stream>>>(acc, out);
}